// Round 1
// baseline (3802.987 us; speedup 1.0000x reference)
//
#include <hip/hip_runtime.h>

#define CIN  256
#define WID  48
#define HWD  2304            // 48*48
#define NTB  64              // ts(16) * b(4)
#define SLICE (4*CIN*HWD)    // elements per timestep slice = 2359296

// ---------------- K1: 3x3 SAME conv, 256->256, fp32 direct ----------------
// grid: (9 hw-tiles, 64 co-groups of 4, 64 tb images), block 256
__global__ __launch_bounds__(256) void conv3x3_k(
    const float* __restrict__ X, const float* __restrict__ Wt,
    const float* __restrict__ Bs, float* __restrict__ Y)
{
    const int tid = threadIdx.x;
    const int hw  = blockIdx.x * 256 + tid;   // 0..2303
    const int co0 = blockIdx.y * 4;
    const int tb  = blockIdx.z;
    const int h = hw / WID, w = hw % WID;
    const bool hm = (h > 0), hp = (h < WID-1), wm = (w > 0), wp = (w < WID-1);

    const float* xb = X  + (size_t)tb * CIN * HWD + hw;
    const float* wb = Wt + (size_t)co0 * CIN * 9;

    float a0 = Bs[co0+0], a1 = Bs[co0+1], a2 = Bs[co0+2], a3 = Bs[co0+3];

    for (int ci = 0; ci < CIN; ++ci) {
        const float* xp = xb + ci * HWD;
        const float x00 = (hm && wm) ? xp[-WID-1] : 0.f;
        const float x01 =  hm        ? xp[-WID]   : 0.f;
        const float x02 = (hm && wp) ? xp[-WID+1] : 0.f;
        const float x10 =  wm        ? xp[-1]     : 0.f;
        const float x11 =              xp[0];
        const float x12 =  wp        ? xp[1]      : 0.f;
        const float x20 = (hp && wm) ? xp[WID-1]  : 0.f;
        const float x21 =  hp        ? xp[WID]    : 0.f;
        const float x22 = (hp && wp) ? xp[WID+1]  : 0.f;

        const float* q0 = wb + ci * 9;            // uniform -> s_load
        const float* q1 = q0 + CIN*9;
        const float* q2 = q0 + 2*CIN*9;
        const float* q3 = q0 + 3*CIN*9;

        a0 += x00*q0[0] + x01*q0[1] + x02*q0[2]
            + x10*q0[3] + x11*q0[4] + x12*q0[5]
            + x20*q0[6] + x21*q0[7] + x22*q0[8];
        a1 += x00*q1[0] + x01*q1[1] + x02*q1[2]
            + x10*q1[3] + x11*q1[4] + x12*q1[5]
            + x20*q1[6] + x21*q1[7] + x22*q1[8];
        a2 += x00*q2[0] + x01*q2[1] + x02*q2[2]
            + x10*q2[3] + x11*q2[4] + x12*q2[5]
            + x20*q2[6] + x21*q2[7] + x22*q2[8];
        a3 += x00*q3[0] + x01*q3[1] + x02*q3[2]
            + x10*q3[3] + x11*q3[4] + x12*q3[5]
            + x20*q3[6] + x21*q3[7] + x22*q3[8];
    }

    float* yp = Y + (size_t)tb * CIN * HWD + hw;
    yp[(size_t)(co0+0)*HWD] = a0;
    yp[(size_t)(co0+1)*HWD] = a1;
    yp[(size_t)(co0+2)*HWD] = a2;
    yp[(size_t)(co0+3)*HWD] = a3;
}

// ---------------- K2: LI scan over ts, in place on Y ----------------
// v_new = v + 0.1*((0 - v) + i_old);  i_new = i_old - 0.2*i_old + x;  out = v_new
__global__ __launch_bounds__(256) void li_scan_k(float* __restrict__ Y)
{
    const int n = blockIdx.x * 256 + threadIdx.x;   // 0..SLICE-1 (b,c,h,w)
    float v = 0.f, cur = 0.f;                       // cur = synaptic current i
    #pragma unroll
    for (int t = 0; t < 16; ++t) {
        const size_t idx = (size_t)t * SLICE + n;
        const float x = Y[idx];
        v = v + 0.1f * ((0.f - v) + cur);
        Y[idx] = v;
        cur = cur - 0.2f * cur + x;
    }
}

// ---------------- K3: 1x1 conv heads (12 box + 9 cls) ----------------
// thread per (tb, hw); 21 accumulators; weight reads are wave-uniform (scalar)
__global__ __launch_bounds__(256) void heads_k(
    const float* __restrict__ V,
    const float* __restrict__ bw, const float* __restrict__ bb,
    const float* __restrict__ cw, const float* __restrict__ cb,
    float* __restrict__ out)
{
    const int n  = blockIdx.x * 256 + threadIdx.x;  // 0..(64*2304-1)
    const int tb = n / HWD;
    const int hw = n % HWD;
    const float* vp = V + (size_t)tb * CIN * HWD + hw;

    float aB[12], aC[9];
    #pragma unroll
    for (int o = 0; o < 12; ++o) aB[o] = bb[o];
    #pragma unroll
    for (int o = 0; o < 9;  ++o) aC[o] = cb[o];

    for (int ci = 0; ci < CIN; ++ci) {
        const float v = vp[(size_t)ci * HWD];
        #pragma unroll
        for (int o = 0; o < 12; ++o) aB[o] += v * bw[o*CIN + ci];
        #pragma unroll
        for (int o = 0; o < 9;  ++o) aC[o] += v * cw[o*CIN + ci];
    }

    float* ob = out + (size_t)tb * 12 * HWD + hw;
    #pragma unroll
    for (int o = 0; o < 12; ++o) ob[(size_t)o * HWD] = aB[o];
    float* oc = out + (size_t)12 * NTB * HWD + (size_t)tb * 9 * HWD + hw;
    #pragma unroll
    for (int o = 0; o < 9;  ++o) oc[(size_t)o * HWD] = aC[o];
}

extern "C" void kernel_launch(void* const* d_in, const int* in_sizes, int n_in,
                              void* d_out, int out_size, void* d_ws, size_t ws_size,
                              hipStream_t stream)
{
    const float* X   = (const float*)d_in[0];  // (16,4,256,48,48)
    const float* cw3 = (const float*)d_in[1];  // (256,256,3,3)
    const float* cb3 = (const float*)d_in[2];  // (256,)
    const float* bw  = (const float*)d_in[3];  // (12,256,1,1)
    const float* bb  = (const float*)d_in[4];  // (12,)
    const float* clw = (const float*)d_in[5];  // (9,256,1,1)
    const float* clb = (const float*)d_in[6];  // (9,)
    float* out = (float*)d_out;
    float* Y   = (float*)d_ws;                 // 16*4*256*2304 floats = 151 MB

    conv3x3_k<<<dim3(9, 64, 64), 256, 0, stream>>>(X, cw3, cb3, Y);
    li_scan_k<<<dim3(SLICE / 256), 256, 0, stream>>>(Y);
    heads_k<<<dim3(NTB * HWD / 256), 256, 0, stream>>>(Y, bw, bb, clw, clb, out);
}

// Round 2
// 857.292 us; speedup vs baseline: 4.4360x; 4.4360x over previous
//
#include <hip/hip_runtime.h>

#define CIN    256
#define WID    48
#define HWD    2304            // 48*48
#define NTB    64              // ts(16) * b(4)
#define SLICE  (4*CIN*HWD)     // elements per timestep slice
#define KSTEPS 72              // K = 9 taps * 256 ci = 2304 = 72 * 32

typedef __attribute__((ext_vector_type(8))) short short8v;  // 8 bf16 (4 VGPRs)
typedef __attribute__((ext_vector_type(4))) float f32x4;

__device__ __forceinline__ unsigned short f2bf(float f) {
    unsigned u = __float_as_uint(f);
    u = (u + 0x7fffu + ((u >> 16) & 1u)) >> 16;   // RNE
    return (unsigned short)u;
}
__device__ __forceinline__ float bf2f(unsigned short s) {
    return __uint_as_float(((unsigned)s) << 16);
}

// ---- K1: weights fp32 -> bf16, MFMA tile layout At[mb][ks][m(128)][kk(32)]
// k-order: k = tap*256 + ci  (tap-major so each 32-wide K-step is one tap)
__global__ __launch_bounds__(256) void prep_w_k(const float* __restrict__ Wt,
                                                unsigned short* __restrict__ At)
{
    const int idx = blockIdx.x * 256 + threadIdx.x;   // < 2*72*128*32 = 589824
    const int kk = idx & 31;
    const int m  = (idx >> 5) & 127;
    const int r  = idx >> 12;
    const int ks = r % KSTEPS, mb = r / KSTEPS;
    const int co = mb * 128 + m;
    const int tap = ks >> 3;
    const int ci  = (ks & 7) * 32 + kk;
    At[idx] = f2bf(Wt[(size_t)co * 2304 + ci * 9 + tap]);
}

// ---- K2: implicit-GEMM conv via MFMA. C[co][p] , p = tb*2304 + hw.
// grid (1152 N-tiles, 2 M-tiles), block 256 (4 waves, each 64x64 out)
__global__ __launch_bounds__(256) void conv_mfma_k(
    const float* __restrict__ X, const unsigned short* __restrict__ At,
    const float* __restrict__ Bs, unsigned short* __restrict__ Y)
{
    __shared__ short lds_a[128 * 40];   // [m][k] rows padded to 40 shorts (80B)
    __shared__ short lds_b[128 * 40];   // [n][k] (im2col^T) rows padded

    const int tid = threadIdx.x;
    const int bx  = blockIdx.x;          // 0..1151
    const int by  = blockIdx.y;          // 0..1
    const int tb  = bx / 18;
    const int hw0 = (bx % 18) * 128;
    const int m0  = by * 128;

    const int wave = tid >> 6, lane = tid & 63;
    const int wm = wave >> 1, wn = wave & 1;
    const int lr = lane & 15, lg = lane >> 4;

    // staging maps: 512 items, 2 per thread
    const int bn = tid & 127;            // B: pixel-in-tile (same for both items)
    const int bg = tid >> 7;             // B: k-group 0/1 (+2 for item 1)
    const int am = tid >> 2;             // A: m for item 0 (item1: +64)
    const int ag = tid & 3;              // A: k-group

    const int hw_i = hw0 + bn;
    const int h_i = hw_i / WID, w_i = hw_i - (hw_i / WID) * WID;
    const float* xbase = X + (size_t)tb * CIN * HWD;
    const unsigned short* abase = At + (size_t)by * KSTEPS * 4096;

    f32x4 acc[4][4];
    const f32x4 zero = {0.f, 0.f, 0.f, 0.f};
    #pragma unroll
    for (int i = 0; i < 4; ++i)
        #pragma unroll
        for (int j = 0; j < 4; ++j) acc[i][j] = zero;

    short8v areg0, areg1;
    short8v breg[2];

    auto load_step = [&](int ks) {
        const int tap = ks >> 3;
        const int dh = tap / 3 - 1, dw = tap % 3 - 1;
        const int ci0 = (ks & 7) * 32;
        // A: fully coalesced 16B loads from tiled layout
        const unsigned short* ap = abase + (size_t)ks * 4096 + tid * 8;
        areg0 = *(const short8v*)ap;
        areg1 = *(const short8v*)(ap + 2048);
        // B: 8 masked fp32 loads per item, convert to bf16
        const int hh = h_i + dh, ww = w_i + dw;
        const bool valid = ((unsigned)hh < (unsigned)WID) && ((unsigned)ww < (unsigned)WID);
        const float* xp = xbase + (size_t)ci0 * HWD + hh * WID + ww;
        #pragma unroll
        for (int s = 0; s < 2; ++s) {
            const int kg = bg + s * 2;
            #pragma unroll
            for (int e = 0; e < 8; ++e) {
                float v = valid ? xp[(size_t)(kg * 8 + e) * HWD] : 0.f;
                breg[s][e] = (short)f2bf(v);
            }
        }
    };

    load_step(0);

    for (int ks = 0; ks < KSTEPS; ++ks) {
        __syncthreads();                          // prev MFMA reads done
        *(short8v*)(&lds_a[am * 40 + ag * 8])        = areg0;
        *(short8v*)(&lds_a[(am + 64) * 40 + ag * 8]) = areg1;
        *(short8v*)(&lds_b[bn * 40 + bg * 8])        = breg[0];
        *(short8v*)(&lds_b[bn * 40 + (bg + 2) * 8])  = breg[1];
        __syncthreads();                          // tiles ready
        if (ks + 1 < KSTEPS) load_step(ks + 1);   // prefetch next (overlaps MFMA)

        short8v af[4], bf[4];
        #pragma unroll
        for (int mi = 0; mi < 4; ++mi)
            af[mi] = *(const short8v*)(&lds_a[(wm * 64 + mi * 16 + lr) * 40 + lg * 8]);
        #pragma unroll
        for (int ni = 0; ni < 4; ++ni)
            bf[ni] = *(const short8v*)(&lds_b[(wn * 64 + ni * 16 + lr) * 40 + lg * 8]);
        #pragma unroll
        for (int mi = 0; mi < 4; ++mi)
            #pragma unroll
            for (int ni = 0; ni < 4; ++ni)
                acc[mi][ni] = __builtin_amdgcn_mfma_f32_16x16x32_bf16(
                    af[mi], bf[ni], acc[mi][ni], 0, 0, 0);
    }

    // epilogue: D row=(lane>>4)*4+r, col=lane&15 ; add bias, write bf16
    const int mbase = m0 + wm * 64;
    const int nbase = hw0 + wn * 64;
    #pragma unroll
    for (int mi = 0; mi < 4; ++mi) {
        #pragma unroll
        for (int r = 0; r < 4; ++r) {
            const int m = mbase + mi * 16 + lg * 4 + r;
            const float bias = Bs[m];
            unsigned short* yp = Y + ((size_t)tb * CIN + m) * HWD + nbase;
            #pragma unroll
            for (int ni = 0; ni < 4; ++ni)
                yp[ni * 16 + lr] = f2bf(acc[mi][ni][r] + bias);
        }
    }
}

// ---- K3: LI scan in place on bf16 Y, 2 elems/thread (uint)
__global__ __launch_bounds__(256) void li_scan_k(unsigned int* __restrict__ Y)
{
    const int n = blockIdx.x * 256 + threadIdx.x;   // pair index
    float v0 = 0.f, v1 = 0.f, c0 = 0.f, c1 = 0.f;
    #pragma unroll
    for (int t = 0; t < 16; ++t) {
        const size_t idx = (size_t)t * (SLICE / 2) + n;
        const unsigned u = Y[idx];
        const float x0 = bf2f((unsigned short)(u & 0xffff));
        const float x1 = bf2f((unsigned short)(u >> 16));
        v0 = v0 + 0.1f * ((0.0f - v0) + c0);
        v1 = v1 + 0.1f * ((0.0f - v1) + c1);
        Y[idx] = (unsigned)f2bf(v0) | ((unsigned)f2bf(v1) << 16);
        c0 = c0 - 0.2f * c0 + x0;
        c1 = c1 - 0.2f * c1 + x1;
    }
}

// ---- K4: 1x1 heads, 2 pixels/thread, weights wave-uniform
__global__ __launch_bounds__(256) void heads_k(
    const unsigned int* __restrict__ V,
    const float* __restrict__ bw, const float* __restrict__ bb,
    const float* __restrict__ cw, const float* __restrict__ cb,
    float* __restrict__ out)
{
    const int n = blockIdx.x * 256 + threadIdx.x;      // 0..73727 pixel pairs
    const int tb  = n / (HWD / 2);
    const int hw2 = n - tb * (HWD / 2);
    const unsigned int* vp = V + (size_t)tb * CIN * (HWD / 2) + hw2;

    float b0[12], b1[12], cl0[9], cl1[9];
    #pragma unroll
    for (int o = 0; o < 12; ++o) { b0[o] = bb[o]; b1[o] = bb[o]; }
    #pragma unroll
    for (int o = 0; o < 9;  ++o) { cl0[o] = cb[o]; cl1[o] = cb[o]; }

    for (int ci = 0; ci < CIN; ++ci) {
        const unsigned u = vp[(size_t)ci * (HWD / 2)];
        const float lo = bf2f((unsigned short)(u & 0xffff));
        const float hi = bf2f((unsigned short)(u >> 16));
        #pragma unroll
        for (int o = 0; o < 12; ++o) {
            const float w = bw[o * CIN + ci];
            b0[o] += lo * w; b1[o] += hi * w;
        }
        #pragma unroll
        for (int o = 0; o < 9; ++o) {
            const float w = cw[o * CIN + ci];
            cl0[o] += lo * w; cl1[o] += hi * w;
        }
    }

    const int hw = hw2 * 2;
    float* ob = out + (size_t)tb * 12 * HWD + hw;
    #pragma unroll
    for (int o = 0; o < 12; ++o) { ob[(size_t)o * HWD] = b0[o]; ob[(size_t)o * HWD + 1] = b1[o]; }
    float* oc = out + (size_t)12 * NTB * HWD + (size_t)tb * 9 * HWD + hw;
    #pragma unroll
    for (int o = 0; o < 9;  ++o) { oc[(size_t)o * HWD] = cl0[o]; oc[(size_t)o * HWD + 1] = cl1[o]; }
}

extern "C" void kernel_launch(void* const* d_in, const int* in_sizes, int n_in,
                              void* d_out, int out_size, void* d_ws, size_t ws_size,
                              hipStream_t stream)
{
    const float* X   = (const float*)d_in[0];  // (16,4,256,48,48)
    const float* cw3 = (const float*)d_in[1];  // (256,256,3,3)
    const float* cb3 = (const float*)d_in[2];  // (256,)
    const float* bw  = (const float*)d_in[3];  // (12,256,1,1)
    const float* bb  = (const float*)d_in[4];  // (12,)
    const float* clw = (const float*)d_in[5];  // (9,256,1,1)
    const float* clb = (const float*)d_in[6];  // (9,)
    float* out = (float*)d_out;

    unsigned short* At = (unsigned short*)d_ws;                      // 1.18 MB
    unsigned short* Y  = (unsigned short*)((char*)d_ws + 1179648);   // bf16, 75.5 MB

    prep_w_k <<<2304, 256, 0, stream>>>(cw3, At);
    conv_mfma_k<<<dim3(1152, 2), 256, 0, stream>>>(X, At, cb3, Y);
    li_scan_k<<<SLICE / 512, 256, 0, stream>>>((unsigned int*)Y);
    heads_k  <<<NTB * HWD / 512, 256, 0, stream>>>((const unsigned int*)Y,
                                                   bw, bb, clw, clb, out);
}

// Round 3
// 442.722 us; speedup vs baseline: 8.5900x; 1.9364x over previous
//
#include <hip/hip_runtime.h>

#define CIN    256
#define WID    48
#define HWD    2304            // 48*48
#define NTB    64              // ts(16) * b(4)
#define SLICE  (4*CIN*HWD)     // elements per timestep slice
#define KSTEPS 72              // K = 9 taps * 256 ci = 2304 = 72 * 32

// workspace layout (bytes); known-safe ws floor is 150,994,944
#define WS_AT  4096            // A-tiles: 2*72*512*16 = 1,179,648
#define WS_XT  1183744         // Xt half: 32*2304*256*2 = 37,748,736
#define WS_Y   38932480        // Y bf16 : 64*256*2304*2 = 75,497,472 (ends 114,429,952)

typedef __attribute__((ext_vector_type(8))) short short8v;  // 8 bf16
typedef __attribute__((ext_vector_type(4))) float f32x4;

__device__ __forceinline__ unsigned short f2bf(float f) {
    unsigned u = __float_as_uint(f);
    u = (u + 0x7fffu + ((u >> 16) & 1u)) >> 16;   // RNE
    return (unsigned short)u;
}
__device__ __forceinline__ float bf2f(unsigned short s) {
    return __uint_as_float(((unsigned)s) << 16);
}

__device__ __forceinline__ void gload_lds16(const void* g, void* l) {
    __builtin_amdgcn_global_load_lds(
        (const __attribute__((address_space(1))) unsigned int*)g,
        (__attribute__((address_space(3))) unsigned int*)l, 16, 0, 0);
}

// ---- prep_w: fp32 W -> bf16 A-tiles, exact LDS image order:
// At[(mb*72+ks)*512 + slot]*8 + e ; slot = chunk*128 + m ; ci = (ks&7)*32 + chunk*8 + e
__global__ __launch_bounds__(256) void prep_w_k(const float* __restrict__ Wt,
                                                unsigned short* __restrict__ At)
{
    const int idx = blockIdx.x * 256 + threadIdx.x;   // < 589824
    const int e    = idx & 7;
    const int slot = (idx >> 3) & 511;
    const int rem  = idx >> 12;
    const int ks   = rem % KSTEPS, mb = rem / KSTEPS;
    const int chunk = slot >> 7, m = slot & 127;
    const int co  = mb * 128 + m;
    const int tap = ks >> 3;
    const int ci  = (ks & 7) * 32 + chunk * 8 + e;
    At[idx] = f2bf(Wt[(size_t)co * 2304 + ci * 9 + tap]);
}

// ---- prep_x: X fp32 [32tb][ci][px] -> Xt bf16 [32tb][px][ci] via LDS transpose
__global__ __launch_bounds__(256) void prep_x_k(const float* __restrict__ X,
                                                unsigned short* __restrict__ Xt)
{
    __shared__ unsigned short t_[64][72];
    const int tid = threadIdx.x;
    const int px0 = blockIdx.x * 64;
    const int ci0 = blockIdx.y * 64;
    const int tb  = blockIdx.z;

    const int ci_l = tid >> 2, pg = (tid & 3) * 16;
    const float* xp = X + ((size_t)tb * CIN + ci0 + ci_l) * HWD + px0 + pg;
    #pragma unroll
    for (int q = 0; q < 4; ++q) {
        f32x4 v = *(const f32x4*)(xp + q * 4);
        #pragma unroll
        for (int e = 0; e < 4; ++e)
            t_[pg + q * 4 + e][ci_l] = f2bf(v[e]);
    }
    __syncthreads();
    const int px_l = tid >> 2, cg = (tid & 3) * 16;
    unsigned short* op = Xt + ((size_t)tb * HWD + px0 + px_l) * CIN + ci0 + cg;
    *(short8v*)op       = *(const short8v*)&t_[px_l][cg];
    *(short8v*)(op + 8) = *(const short8v*)&t_[px_l][cg + 8];
}

// ---- conv: implicit GEMM, m97 structure (global_load_lds w16 + 2-phase dbuf)
// grid 1152: nt(576 = 32tb x 18 hw-tiles) x by(2), XCD-swizzled, M fastest
__global__ __launch_bounds__(256) void conv_mfma_k(
    const unsigned short* __restrict__ Xt, const unsigned short* __restrict__ At,
    const float* __restrict__ Bs, unsigned short* __restrict__ Y,
    const unsigned short* __restrict__ zp, int tb_base)
{
    __shared__ short ldsA[2][4096];   // [buf][chunk(4)][row(128)][8]  8 KB each
    __shared__ short ldsB[2][4096];

    const int tid = threadIdx.x;
    const int wv  = tid >> 6, ln = tid & 63;
    const int lr  = ln & 15,  lg = ln >> 4;
    const int wm  = wv >> 1,  wn = wv & 1;

    // bijective XCD swizzle, nwg=1152 (q=144, r=0); M-tile fastest in logical id
    const int orig = blockIdx.x;
    const int wg   = (orig & 7) * 144 + (orig >> 3);
    const int by   = wg & 1;
    const int nt   = wg >> 1;            // 0..575
    const int tb_l = nt / 18;
    const int hw0  = (nt % 18) * 128;

    // this thread's two B rows: r0 = ln, r1 = 64+ln (chunk = wv)
    const int p0 = hw0 + ln, p1 = p0 + 64;
    const int h0 = p0 / WID, w0 = p0 - h0 * WID;
    const int h1 = p1 / WID, w1 = p1 - h1 * WID;
    const unsigned short* xb = Xt + (size_t)tb_l * HWD * CIN;
    const unsigned short* b0base = xb + (size_t)p0 * CIN + wv * 8;
    const unsigned short* b1base = xb + (size_t)p1 * CIN + wv * 8;
    const unsigned short* ab = At + (size_t)by * KSTEPS * 4096;

    f32x4 acc[4][4];
    const f32x4 zero = {0.f, 0.f, 0.f, 0.f};
    #pragma unroll
    for (int i = 0; i < 4; ++i)
        #pragma unroll
        for (int j = 0; j < 4; ++j) acc[i][j] = zero;

    auto stage = [&](int ks, int buf) {
        const int tap = ks >> 3;
        const int dh = tap / 3 - 1, dw = tap - (tap / 3) * 3 - 1;
        const int koff = (dh * WID + dw) * CIN + (ks & 7) * 32;   // elements
        const bool v0 = ((unsigned)(h0 + dh) < WID) && ((unsigned)(w0 + dw) < WID);
        const bool v1 = ((unsigned)(h1 + dh) < WID) && ((unsigned)(w1 + dw) < WID);
        const unsigned short* ap = ab + (size_t)ks * 4096 + wv * 1024 + ln * 8;
        gload_lds16(ap,       &ldsA[buf][wv * 1024]);
        gload_lds16(ap + 512, &ldsA[buf][wv * 1024 + 512]);
        const unsigned short* bp0 = v0 ? b0base + koff : zp;
        const unsigned short* bp1 = v1 ? b1base + koff : zp;
        gload_lds16(bp0, &ldsB[buf][wv * 1024]);
        gload_lds16(bp1, &ldsB[buf][wv * 1024 + 512]);
    };

    stage(0, 0);
    __syncthreads();                       // vmcnt(0) drain + barrier

    for (int ks = 0; ks < KSTEPS; ++ks) {
        const int cur = ks & 1;
        if (ks + 1 < KSTEPS) stage(ks + 1, cur ^ 1);   // prefetch next tile
        short8v a_[4], b_[4];
        #pragma unroll
        for (int mi = 0; mi < 4; ++mi)
            a_[mi] = *(const short8v*)&ldsA[cur][lg * 1024 + (wm * 64 + mi * 16 + lr) * 8];
        #pragma unroll
        for (int ni = 0; ni < 4; ++ni)
            b_[ni] = *(const short8v*)&ldsB[cur][lg * 1024 + (wn * 64 + ni * 16 + lr) * 8];
        #pragma unroll
        for (int mi = 0; mi < 4; ++mi)
            #pragma unroll
            for (int ni = 0; ni < 4; ++ni)
                acc[mi][ni] = __builtin_amdgcn_mfma_f32_16x16x32_bf16(
                    a_[mi], b_[ni], acc[mi][ni], 0, 0, 0);
        __syncthreads();                   // drains this step's loads, frees cur
    }

    // epilogue: D row=(lane>>4)*4+r (m), col=lane&15 (pixel)
    const int mbase = by * 128 + wm * 64;
    const int nbase = hw0 + wn * 64;
    const int tbg   = tb_base + tb_l;
    #pragma unroll
    for (int mi = 0; mi < 4; ++mi) {
        #pragma unroll
        for (int r = 0; r < 4; ++r) {
            const int m = mbase + mi * 16 + lg * 4 + r;
            const float bias = Bs[m];
            unsigned short* yp = Y + ((size_t)tbg * CIN + m) * HWD + nbase;
            #pragma unroll
            for (int ni = 0; ni < 4; ++ni)
                yp[ni * 16 + lr] = f2bf(acc[mi][ni][r] + bias);
        }
    }
}

// ---- LI scan in place on bf16 Y, 2 elems/thread
__global__ __launch_bounds__(256) void li_scan_k(unsigned int* __restrict__ Y)
{
    const int n = blockIdx.x * 256 + threadIdx.x;
    float v0 = 0.f, v1 = 0.f, c0 = 0.f, c1 = 0.f;
    #pragma unroll
    for (int t = 0; t < 16; ++t) {
        const size_t idx = (size_t)t * (SLICE / 2) + n;
        const unsigned u = Y[idx];
        const float x0 = bf2f((unsigned short)(u & 0xffff));
        const float x1 = bf2f((unsigned short)(u >> 16));
        v0 = v0 + 0.1f * ((0.0f - v0) + c0);
        v1 = v1 + 0.1f * ((0.0f - v1) + c1);
        Y[idx] = (unsigned)f2bf(v0) | ((unsigned)f2bf(v1) << 16);
        c0 = c0 - 0.2f * c0 + x0;
        c1 = c1 - 0.2f * c1 + x1;
    }
}

// ---- 1x1 heads, 2 pixels/thread
__global__ __launch_bounds__(256) void heads_k(
    const unsigned int* __restrict__ V,
    const float* __restrict__ bw, const float* __restrict__ bb,
    const float* __restrict__ cw, const float* __restrict__ cb,
    float* __restrict__ out)
{
    const int n = blockIdx.x * 256 + threadIdx.x;
    const int tb  = n / (HWD / 2);
    const int hw2 = n - tb * (HWD / 2);
    const unsigned int* vp = V + (size_t)tb * CIN * (HWD / 2) + hw2;

    float b0[12], b1[12], cl0[9], cl1[9];
    #pragma unroll
    for (int o = 0; o < 12; ++o) { b0[o] = bb[o]; b1[o] = bb[o]; }
    #pragma unroll
    for (int o = 0; o < 9;  ++o) { cl0[o] = cb[o]; cl1[o] = cb[o]; }

    for (int ci = 0; ci < CIN; ++ci) {
        const unsigned u = vp[(size_t)ci * (HWD / 2)];
        const float lo = bf2f((unsigned short)(u & 0xffff));
        const float hi = bf2f((unsigned short)(u >> 16));
        #pragma unroll
        for (int o = 0; o < 12; ++o) {
            const float w = bw[o * CIN + ci];
            b0[o] += lo * w; b1[o] += hi * w;
        }
        #pragma unroll
        for (int o = 0; o < 9; ++o) {
            const float w = cw[o * CIN + ci];
            cl0[o] += lo * w; cl1[o] += hi * w;
        }
    }

    const int hw = hw2 * 2;
    float* ob = out + (size_t)tb * 12 * HWD + hw;
    #pragma unroll
    for (int o = 0; o < 12; ++o) { ob[(size_t)o * HWD] = b0[o]; ob[(size_t)o * HWD + 1] = b1[o]; }
    float* oc = out + (size_t)12 * NTB * HWD + (size_t)tb * 9 * HWD + hw;
    #pragma unroll
    for (int o = 0; o < 9;  ++o) { oc[(size_t)o * HWD] = cl0[o]; oc[(size_t)o * HWD + 1] = cl1[o]; }
}

extern "C" void kernel_launch(void* const* d_in, const int* in_sizes, int n_in,
                              void* d_out, int out_size, void* d_ws, size_t ws_size,
                              hipStream_t stream)
{
    const float* X   = (const float*)d_in[0];  // (16,4,256,48,48)
    const float* cw3 = (const float*)d_in[1];  // (256,256,3,3)
    const float* cb3 = (const float*)d_in[2];  // (256,)
    const float* bw  = (const float*)d_in[3];
    const float* bb  = (const float*)d_in[4];
    const float* clw = (const float*)d_in[5];
    const float* clb = (const float*)d_in[6];
    float* out = (float*)d_out;

    const unsigned short* zp = (const unsigned short*)d_ws;               // zero page
    unsigned short* At = (unsigned short*)((char*)d_ws + WS_AT);
    unsigned short* Xt = (unsigned short*)((char*)d_ws + WS_XT);
    unsigned short* Y  = (unsigned short*)((char*)d_ws + WS_Y);

    hipMemsetAsync(d_ws, 0, 4096, stream);
    prep_w_k<<<2304, 256, 0, stream>>>(cw3, At);

    for (int half = 0; half < 2; ++half) {
        const float* Xh = X + (size_t)half * 32 * CIN * HWD;
        prep_x_k<<<dim3(36, 4, 32), 256, 0, stream>>>(Xh, Xt);
        conv_mfma_k<<<1152, 256, 0, stream>>>(Xt, At, cb3, Y, zp, half * 32);
    }

    li_scan_k<<<SLICE / 512, 256, 0, stream>>>((unsigned int*)Y);
    heads_k  <<<NTB * HWD / 512, 256, 0, stream>>>((const unsigned int*)Y,
                                                   bw, bb, clw, clb, out);
}